// Round 14
// baseline (266.522 us; speedup 1.0000x reference)
//
#include <hip/hip_runtime.h>
#include <hip/hip_bf16.h>

#define B_    16
#define N_    640
#define C_    640
#define H_    8
#define D_    80
#define DP_   96          // padded head dim in Qp/Kp row layout (3 x 32)
#define CP_   768         // H_*DP_
#define NSEL_ 2048
#define NTOK_ 10240       // B_*N_
#define NKV_  12288       // NTOK_+NSEL_

typedef short bf16x8 __attribute__((ext_vector_type(8)));
typedef float f32x4  __attribute__((ext_vector_type(4)));
typedef unsigned int u32;
typedef u32 u32x4 __attribute__((ext_vector_type(4)));
typedef unsigned short u16;

#define MFMA16(a,b,c) __builtin_amdgcn_mfma_f32_16x16x32_bf16((a),(b),(c),0,0,0)

// f32 -> bf16 round-to-nearest-even (finite inputs)
static __device__ __forceinline__ u16 f2b(float f) {
  u32 x = __builtin_bit_cast(u32, f);
  x += 0x7fffu + ((x >> 16) & 1u);
  return (u16)(x >> 16);
}

// packed f32x2 -> bf16x2 (RNE), single HW instr
static __device__ __forceinline__ u32 cvtpk(float lo, float hi) {
  u32 r;
  asm("v_cvt_pk_bf16_f32 %0, %1, %2" : "=v"(r) : "v"(lo), "v"(hi));
  return r;
}

// async global->LDS, 16B per lane
static __device__ __forceinline__ void gl16(const void* g, void* l) {
  __builtin_amdgcn_global_load_lds((const __attribute__((address_space(1))) u32*)g,
                                   (__attribute__((address_space(3))) u32*)l, 16, 0, 0);
}

// kv staging permutation: LDS K-row r holds token tokbase + PI(r).
// Chosen so swapped-QK^T output regs are exactly the PV A-fragment elements.
static __device__ __forceinline__ int PI(int r) {
  return ((r >> 2) & 3) * 8 + (r >> 5) * 32 + ((r >> 4) & 1) * 4 + (r & 3);
}

// ---------------- convert x (f32 -> bf16), 4 elems/thread ----------------
__global__ __launch_bounds__(256) void k_convert_x(const float* __restrict__ x,
                                                   u16* __restrict__ xb) {
  int i = blockIdx.x * 256 + threadIdx.x;        // 1,638,400 threads
  float4 v = ((const float4*)x)[i];
  ushort4 o;
  o.x = f2b(v.x); o.y = f2b(v.y); o.z = f2b(v.z); o.w = f2b(v.w);
  ((ushort4*)xb)[i] = o;
}

// ---------------- convert W (f32 -> bf16 transposed) ----------------
__global__ __launch_bounds__(256) void k_convert_w(const float* w0, const float* w1,
                                                   const float* w2, const float* w3,
                                                   u16* t0, u16* t1, u16* t2, u16* t3) {
  const float* W = (blockIdx.z == 0) ? w0 : (blockIdx.z == 1) ? w1 : (blockIdx.z == 2) ? w2 : w3;
  u16*         T = (blockIdx.z == 0) ? t0 : (blockIdx.z == 1) ? t1 : (blockIdx.z == 2) ? t2 : t3;
  __shared__ float tile[32][33];
  int tx = threadIdx.x & 31, ty = threadIdx.x >> 5;   // 32 x 8
  int n0 = blockIdx.x * 32, k0 = blockIdx.y * 32;
#pragma unroll
  for (int r = 0; r < 4; r++)
    tile[ty + 8 * r][tx] = W[(k0 + ty + 8 * r) * C_ + n0 + tx];
  __syncthreads();
#pragma unroll
  for (int r = 0; r < 4; r++)
    T[(n0 + ty + 8 * r) * C_ + k0 + tx] = f2b(tile[tx][ty + 8 * r]);
}

// ---------------- mask -> sel indices (order-preserving) ----------------
__global__ __launch_bounds__(1024) void k_scan(const float* __restrict__ mask,
                                               int* __restrict__ sel) {
  __shared__ int wcnt[16];
  __shared__ int carry;
  int tid = threadIdx.x, lane = tid & 63, wid = tid >> 6;
  float v[10];
#pragma unroll
  for (int r = 0; r < 10; r++) v[r] = mask[r * 1024 + tid];
  if (tid == 0) carry = 0;
  __syncthreads();
  for (int r = 0; r < 10; r++) {
    bool p = v[r] > 0.5f;
    unsigned long long b = __ballot(p);
    if (lane == 0) wcnt[wid] = __popcll(b);
    __syncthreads();
    int off = carry;
    for (int w = 0; w < wid; w++) off += wcnt[w];
    if (p) sel[off + __popcll(b & ((1ull << lane) - 1ull))] = r * 1024 + tid;
    __syncthreads();
    if (tid == 0) {
      int s = 0;
      for (int w = 0; w < 16; w++) s += wcnt[w];
      carry += s;
    }
    __syncthreads();
  }
}

#define QSCALE_ (1.4426950408889634f * 0.11180339887498949f)

// ---------------- fused QKV GEMM: grid 1200, which = f/400 ----------------
// which 0: K -> Kp padded; 1: V -> Vt transposed; 2: Q -> Qp padded+scaled.
// g = f%400: m = g%80, n = g/80 (XCD affinity: 400%8==0 and 80%8==0).
__global__ __launch_bounds__(256) void k_gemm_qkv(const u16* __restrict__ A,
                                                  const u16* __restrict__ WkT,
                                                  const u16* __restrict__ WvT,
                                                  const u16* __restrict__ WqT,
                                                  u16* __restrict__ Kp,
                                                  u16* __restrict__ Vt,
                                                  u16* __restrict__ Qp) {
  __shared__ u16 lA[128 * 32];
  __shared__ u16 lB[128 * 32];
  int tid = threadIdx.x, lane = tid & 63, wid = tid >> 6;
  int l15 = lane & 15, l4 = lane >> 4;
  int f = blockIdx.x;
  int which = f / 400, g = f % 400;
  const u16* BT = (which == 0) ? WkT : (which == 1) ? WvT : WqT;
  int m0 = (g % 80) * 128, n0 = (g / 80) * 128;
  int wr = wid >> 1, wc = wid & 1;
  int tok = tid >> 2, ch = tid & 3;
  int sc = ch ^ (tok & 3);                 // pre-swizzled source chunk
  f32x4 acc[4][4];
#pragma unroll
  for (int mi = 0; mi < 4; mi++)
#pragma unroll
    for (int ni = 0; ni < 4; ni++) acc[mi][ni] = (f32x4){0.f, 0.f, 0.f, 0.f};

  for (int k0 = 0; k0 < C_; k0 += 32) {
    __syncthreads();
    gl16(A  + (m0 + tok)      * C_ + k0 + sc * 8, (char*)lA + tid * 16);
    gl16(A  + (m0 + tok + 64) * C_ + k0 + sc * 8, (char*)lA + 4096 + tid * 16);
    gl16(BT + (n0 + tok)      * C_ + k0 + sc * 8, (char*)lB + tid * 16);
    gl16(BT + (n0 + tok + 64) * C_ + k0 + sc * 8, (char*)lB + 4096 + tid * 16);
    __syncthreads();
    bf16x8 af[4], bfr[4];
#pragma unroll
    for (int mi = 0; mi < 4; mi++) {
      int r = wr * 64 + mi * 16 + l15;
      af[mi] = *(const bf16x8*)((const char*)lA + r * 64 + ((l4 ^ (r & 3)) * 16));
    }
#pragma unroll
    for (int ni = 0; ni < 4; ni++) {
      int r = wc * 64 + ni * 16 + l15;
      bfr[ni] = *(const bf16x8*)((const char*)lB + r * 64 + ((l4 ^ (r & 3)) * 16));
    }
#pragma unroll
    for (int mi = 0; mi < 4; mi++)
#pragma unroll
      for (int ni = 0; ni < 4; ni++) acc[mi][ni] = MFMA16(af[mi], bfr[ni], acc[mi][ni]);
  }

  int cbase = n0 + wc * 64, rbase = m0 + wr * 64;
  if (which == 1) {
    // V: transposed [c][token]
#pragma unroll
    for (int mi = 0; mi < 4; mi++)
#pragma unroll
      for (int ni = 0; ni < 4; ni++) {
        int c = cbase + ni * 16 + l15;
        int r0 = rbase + mi * 16 + l4 * 4;
        ushort4 pk;
        pk.x = f2b(acc[mi][ni][0]); pk.y = f2b(acc[mi][ni][1]);
        pk.z = f2b(acc[mi][ni][2]); pk.w = f2b(acc[mi][ni][3]);
        *(ushort4*)(Vt + c * NKV_ + r0) = pk;
      }
  } else {
    u16* P = (which == 0) ? Kp : Qp;
    float sc2 = (which == 2) ? QSCALE_ : 1.f;
#pragma unroll
    for (int mi = 0; mi < 4; mi++)
#pragma unroll
      for (int ni = 0; ni < 4; ni++) {
        int c = cbase + ni * 16 + l15;
        int h = c / 80, d = c % 80;
#pragma unroll
        for (int rg = 0; rg < 4; rg++) {
          int r = rbase + mi * 16 + l4 * 4 + rg;
          P[r * CP_ + h * DP_ + d] = f2b(acc[mi][ni][rg] * sc2);
        }
      }
  }
}

// ---------------- O GEMM: C[M,N] = A[M,640] * BT[N,640]^T + bias ----------
__global__ __launch_bounds__(256) void k_gemm_o(const u16* __restrict__ A,
                                                const u16* __restrict__ BT,
                                                float* __restrict__ out,
                                                const float* __restrict__ bias) {
  __shared__ u16 lA[128 * 32];
  __shared__ u16 lB[128 * 32];
  int tid = threadIdx.x, lane = tid & 63, wid = tid >> 6;
  int l15 = lane & 15, l4 = lane >> 4;
  int f = blockIdx.x;
  int m0 = (f % 80) * 128, n0 = (f / 80) * 128;
  int wr = wid >> 1, wc = wid & 1;
  int tok = tid >> 2, ch = tid & 3;
  int sc = ch ^ (tok & 3);
  f32x4 acc[4][4];
#pragma unroll
  for (int mi = 0; mi < 4; mi++)
#pragma unroll
    for (int ni = 0; ni < 4; ni++) acc[mi][ni] = (f32x4){0.f, 0.f, 0.f, 0.f};

  for (int k0 = 0; k0 < C_; k0 += 32) {
    __syncthreads();
    gl16(A  + (m0 + tok)      * C_ + k0 + sc * 8, (char*)lA + tid * 16);
    gl16(A  + (m0 + tok + 64) * C_ + k0 + sc * 8, (char*)lA + 4096 + tid * 16);
    gl16(BT + (n0 + tok)      * C_ + k0 + sc * 8, (char*)lB + tid * 16);
    gl16(BT + (n0 + tok + 64) * C_ + k0 + sc * 8, (char*)lB + 4096 + tid * 16);
    __syncthreads();
    bf16x8 af[4], bfr[4];
#pragma unroll
    for (int mi = 0; mi < 4; mi++) {
      int r = wr * 64 + mi * 16 + l15;
      af[mi] = *(const bf16x8*)((const char*)lA + r * 64 + ((l4 ^ (r & 3)) * 16));
    }
#pragma unroll
    for (int ni = 0; ni < 4; ni++) {
      int r = wc * 64 + ni * 16 + l15;
      bfr[ni] = *(const bf16x8*)((const char*)lB + r * 64 + ((l4 ^ (r & 3)) * 16));
    }
#pragma unroll
    for (int mi = 0; mi < 4; mi++)
#pragma unroll
      for (int ni = 0; ni < 4; ni++) acc[mi][ni] = MFMA16(af[mi], bfr[ni], acc[mi][ni]);
  }

  int cbase = n0 + wc * 64, rbase = m0 + wr * 64;
#pragma unroll
  for (int ni = 0; ni < 4; ni++) {
    int c = cbase + ni * 16 + l15;
    float bv = bias[c];
#pragma unroll
    for (int mi = 0; mi < 4; mi++)
#pragma unroll
      for (int rg = 0; rg < 4; rg++)
        out[(rbase + mi * 16 + l4 * 4 + rg) * C_ + c] = acc[mi][ni][rg] + bv;
  }
}

// ---------------- gather sel rows into Kp, sel cols into Vt ----------------
__global__ __launch_bounds__(256) void k_gather(const int* __restrict__ sel,
                                                u16* __restrict__ Kp,
                                                u16* __restrict__ Vt) {
  int i = blockIdx.x;            // 0..2047
  int t = threadIdx.x;
  int s = sel[i];
  const u32* src = (const u32*)(Kp + s * CP_);
  u32* dst = (u32*)(Kp + (NTOK_ + i) * CP_);
  dst[t] = src[t];
  if (t < 128) dst[256 + t] = src[256 + t];
  for (int c = t; c < C_; c += 256)
    Vt[c * NKV_ + NTOK_ + i] = Vt[c * NKV_ + s];
}

// ---------------- flash attention (v10) ----------------
// Round-8 core (2-buffer LDS, batched reg loads, no-max softmax, cvtpk,
// zero-filled K=32 tail). NEW: grid 512 blocks x 320 threads (5 waves x 32
// q-rows = 160 rows/block, 4 q-tiles): per XCD = 64 blocks / 32 CUs =
// EXACTLY 2.0 scheduling rounds (grid 640 gave 2.5 -> 3 rounds, ~17% idle
// tail). f%8 = b%8 keeps XCD frame affinity. Staging = 4 gl16/thread.
__global__ __launch_bounds__(320, 2) void k_attn(const u16* __restrict__ Qp,
                                                 const u16* __restrict__ Kp,
                                                 const u16* __restrict__ Vt,
                                                 u16* __restrict__ Ob) {
  __shared__ u16 smem[2][10240];    // 2 x 20,480 B: Kx32 8192 | Ktail 2048 | V 10240
  int tid = threadIdx.x, lane = tid & 63, wid = tid >> 6;   // wid 0..4
  int l15 = lane & 15, l4 = lane >> 4;
  int f = blockIdx.x;               // 0..511
  int b = f & 15, h = (f >> 4) & 7, qt = f >> 7;   // qt 0..3, XCD affinity
  int q0 = qt * 160 + wid * 32;
  const int NT = 42;
  const bf16x8 kz = {0, 0, 0, 0, 0, 0, 0, 0};

  // Q fragments (pre-scaled by log2e/sqrt(d) in Qp); MFMA B-operand.
  bf16x8 qf[2][2], qtl[2];
#pragma unroll
  for (int m = 0; m < 2; m++) {
    const u16* qrow = Qp + (size_t)(b * N_ + q0 + m * 16 + l15) * CP_ + h * DP_;
#pragma unroll
    for (int kk = 0; kk < 2; kk++)
      qf[m][kk] = *(const bf16x8*)(qrow + kk * 32 + l4 * 8);
    qtl[m] = (l4 < 2) ? *(const bf16x8*)(qrow + 64 + l4 * 8) : kz;
  }

  f32x4 o[2][5];
#pragma unroll
  for (int m = 0; m < 2; m++)
#pragma unroll
    for (int d5 = 0; d5 < 5; d5++) o[m][d5] = (f32x4){0.f, 0.f, 0.f, 0.f};
  float li_[2] = {0.f, 0.f};        // per-lane partial sums of P

  // staging: 1280 slots of 16B, 4 per thread (320 thr), LDS dest linear.
  // slot < 512: K x32 [kk][tok][c]; 512..639: K tail [tok][ch]; 640+: V [vd][c].
  u32 gof[4];
  bool isv[4];
#pragma unroll
  for (int k = 0; k < 4; k++) {
    int s = tid + 320 * k;
    isv[k] = (s >= 640);
    if (s < 512) {
      int kk = s >> 8, rem = s & 255, tok = rem >> 2, c = rem & 3;
      gof[k] = (u32)(PI(tok) * CP_ + h * DP_ + kk * 32 + ((c ^ (tok & 3)) * 8));
    } else if (s < 640) {
      int j = s - 512, tok = j >> 1, ch = j & 1;
      gof[k] = (u32)(PI(tok) * CP_ + h * DP_ + 64 + ch * 8);
    } else {
      int j = s - 640, vd = j >> 3, c = j & 7;
      gof[k] = (u32)((h * D_ + vd) * NKV_ + ((c ^ (vd & 7)) * 8));
    }
  }

  auto stage = [&](int g, int buf) {        // 4 gl16 per thread
    int tokbase = (g < 10) ? (b * N_ + g * 64) : (NTOK_ + (g - 10) * 64);
    size_t kadd = (size_t)tokbase * CP_;
    char* dst = (char*)smem[buf] + tid * 16;
#pragma unroll
    for (int k = 0; k < 4; k++) {
      const u16* src = isv[k] ? (Vt + gof[k] + tokbase) : (Kp + gof[k] + kadd);
      gl16(src, dst + k * 5120);
    }
  };

  stage(0, 0);
  __syncthreads();
  int cur = 0;

  for (int tt = 0; tt < NT; tt++) {
    if (tt + 1 < NT) stage(tt + 1, cur ^ 1);
    const char* kb0 = (const char*)smem[cur];
    const char* vb0 = kb0 + 10240;

    // ---- batched register loads: all K frags, then all V frags ----
    bf16x8 kb[8];
#pragma unroll
    for (int kk = 0; kk < 2; kk++)
#pragma unroll
      for (int nt = 0; nt < 4; nt++) {
        int tk = nt * 16 + l15;
        kb[kk * 4 + nt] = *(const bf16x8*)(kb0 + kk * 4096 + tk * 64 + ((l4 ^ (tk & 3)) * 16));
      }
    bf16x8 kt[4];
#pragma unroll
    for (int nt = 0; nt < 4; nt++) {
      int tk = nt * 16 + l15;
      bf16x8 t = *(const bf16x8*)(kb0 + 8192 + tk * 32 + ((l4 & 1) * 16));
      kt[nt] = (l4 < 2) ? t : kz;
    }
    bf16x8 vb[10];
#pragma unroll
    for (int kk2 = 0; kk2 < 2; kk2++)
#pragma unroll
      for (int d5 = 0; d5 < 5; d5++) {
        int dd = d5 * 16 + l15;
        vb[kk2 * 5 + d5] =
            *(const bf16x8*)(vb0 + dd * 128 + (((kk2 * 4 + l4) ^ (dd & 7)) * 16));
      }

    // QK^T swapped: S^T; C col = q (l15), reg rows = kv (PI-permuted)
    f32x4 s[2][4];
#pragma unroll
    for (int m = 0; m < 2; m++)
#pragma unroll
      for (int nt = 0; nt < 4; nt++) s[m][nt] = (f32x4){0.f, 0.f, 0.f, 0.f};
    __builtin_amdgcn_s_setprio(1);
#pragma unroll
    for (int kk = 0; kk < 2; kk++)
#pragma unroll
      for (int nt = 0; nt < 4; nt++) {
        s[0][nt] = MFMA16(kb[kk * 4 + nt], qf[0][kk], s[0][nt]);
        s[1][nt] = MFMA16(kb[kk * 4 + nt], qf[1][kk], s[1][nt]);
      }
#pragma unroll
    for (int nt = 0; nt < 4; nt++) {      // tail dims 64..79 (zero-filled K=32)
      s[0][nt] = MFMA16(kt[nt], qtl[0], s[0][nt]);
      s[1][nt] = MFMA16(kt[nt], qtl[1], s[1][nt]);
    }
    __builtin_amdgcn_s_setprio(0);

    // P = exp2(S) directly (no max, no rescale) + per-lane partial sum
#pragma unroll
    for (int m = 0; m < 2; m++) {
#pragma unroll
      for (int nt = 0; nt < 4; nt++)
#pragma unroll
        for (int rg = 0; rg < 4; rg++)
          s[m][nt][rg] = exp2f(s[m][nt][rg]);
      f32x4 ps = (s[m][0] + s[m][1]) + (s[m][2] + s[m][3]);
      li_[m] += (ps[0] + ps[1]) + (ps[2] + ps[3]);
    }

    // pack P regs directly into PV A-fragments via v_cvt_pk_bf16_f32
    bf16x8 pa[2][2];
#pragma unroll
    for (int m = 0; m < 2; m++)
#pragma unroll
      for (int kk2 = 0; kk2 < 2; kk2++) {
        u32x4 w;
        w.x = cvtpk(s[m][2 * kk2][0],     s[m][2 * kk2][1]);
        w.y = cvtpk(s[m][2 * kk2][2],     s[m][2 * kk2][3]);
        w.z = cvtpk(s[m][2 * kk2 + 1][0], s[m][2 * kk2 + 1][1]);
        w.w = cvtpk(s[m][2 * kk2 + 1][2], s[m][2 * kk2 + 1][3]);
        pa[m][kk2] = __builtin_bit_cast(bf16x8, w);
      }

    // PV from registers
    __builtin_amdgcn_s_setprio(1);
#pragma unroll
    for (int kk2 = 0; kk2 < 2; kk2++)
#pragma unroll
      for (int d5 = 0; d5 < 5; d5++) {
        o[0][d5] = MFMA16(pa[0][kk2], vb[kk2 * 5 + d5], o[0][d5]);
        o[1][d5] = MFMA16(pa[1][kk2], vb[kk2 * 5 + d5], o[1][d5]);
      }
    __builtin_amdgcn_s_setprio(0);

    __syncthreads();               // drains vmcnt: next buffer ready
    cur ^= 1;
  }

  // epilogue: one cross-lane row-sum reduce, then O / l -> Ob bf16
#pragma unroll
  for (int m = 0; m < 2; m++) {
    li_[m] += __shfl_xor(li_[m], 16);
    li_[m] += __shfl_xor(li_[m], 32);
  }
#pragma unroll
  for (int m = 0; m < 2; m++)
#pragma unroll
    for (int rg = 0; rg < 4; rg++) {
      float lv = __shfl(li_[m], l4 * 4 + rg);
      float inv = 1.f / lv;
#pragma unroll
      for (int d5 = 0; d5 < 5; d5++) {
        int r = b * N_ + q0 + m * 16 + l4 * 4 + rg;
        Ob[(size_t)r * C_ + h * D_ + d5 * 16 + l15] = f2b(o[m][d5][rg] * inv);
      }
    }
}

// ---------------- launch ----------------
extern "C" void kernel_launch(void* const* d_in, const int* in_sizes, int n_in,
                              void* d_out, int out_size, void* d_ws, size_t ws_size,
                              hipStream_t stream) {
  (void)in_sizes; (void)n_in; (void)out_size; (void)ws_size;
  const float* x    = (const float*)d_in[0];
  const float* Wq   = (const float*)d_in[1];
  const float* Wk   = (const float*)d_in[2];
  const float* Wv   = (const float*)d_in[3];
  const float* Wo   = (const float*)d_in[4];
  const float* bo   = (const float*)d_in[5];
  const float* mask = (const float*)d_in[6];

  // Workspace layout (peak 66,723,840 B). Ob aliases xb (xb's last reader
  // k_gemm_qkv precedes the first Ob write, stream-ordered).
  char* ws = (char*)d_ws;
  u16* xb  = (u16*)(ws + 0);          // 13,107,200
  u16* Ob  = xb;                      // alias (see above)
  u16* WqT = (u16*)(ws + 13107200);   //    819,200
  u16* WkT = (u16*)(ws + 13926400);
  u16* WvT = (u16*)(ws + 14745600);
  u16* WoT = (u16*)(ws + 15564800);
  u16* Qp  = (u16*)(ws + 16384000);   // 15,728,640
  u16* Kp  = (u16*)(ws + 32112640);   // 18,874,368
  u16* Vt  = (u16*)(ws + 50987008);   // 15,728,640
  int* sel = (int*)(ws + 66715648);   //      8,192

  k_convert_x<<<6400, 256, 0, stream>>>(x, xb);
  k_convert_w<<<dim3(20, 20, 4), 256, 0, stream>>>(Wq, Wk, Wv, Wo, WqT, WkT, WvT, WoT);
  k_scan<<<1, 1024, 0, stream>>>(mask, sel);
  k_gemm_qkv<<<1200, 256, 0, stream>>>(xb, WkT, WvT, WqT, Kp, Vt, Qp);
  k_gather<<<2048, 256, 0, stream>>>(sel, Kp, Vt);
  k_attn<<<512, 320, 0, stream>>>(Qp, Kp, Vt, Ob);
  k_gemm_o<<<400, 256, 0, stream>>>(Ob, WoT, (float*)d_out, bo);
}

// Round 16
// 229.053 us; speedup vs baseline: 1.1636x; 1.1636x over previous
//
#include <hip/hip_runtime.h>
#include <hip/hip_bf16.h>

#define B_    16
#define N_    640
#define C_    640
#define H_    8
#define D_    80
#define DP_   96          // padded head dim in Qp/Kp row layout (3 x 32)
#define CP_   768         // H_*DP_
#define NSEL_ 2048
#define NTOK_ 10240       // B_*N_
#define NKV_  12288       // NTOK_+NSEL_

typedef short bf16x8 __attribute__((ext_vector_type(8)));
typedef float f32x4  __attribute__((ext_vector_type(4)));
typedef unsigned int u32;
typedef u32 u32x4 __attribute__((ext_vector_type(4)));
typedef unsigned short u16;

#define MFMA16(a,b,c) __builtin_amdgcn_mfma_f32_16x16x32_bf16((a),(b),(c),0,0,0)

// f32 -> bf16 round-to-nearest-even (finite inputs)
static __device__ __forceinline__ u16 f2b(float f) {
  u32 x = __builtin_bit_cast(u32, f);
  x += 0x7fffu + ((x >> 16) & 1u);
  return (u16)(x >> 16);
}

// packed f32x2 -> bf16x2 (RNE), single HW instr
static __device__ __forceinline__ u32 cvtpk(float lo, float hi) {
  u32 r;
  asm("v_cvt_pk_bf16_f32 %0, %1, %2" : "=v"(r) : "v"(lo), "v"(hi));
  return r;
}

// async global->LDS, 16B per lane
static __device__ __forceinline__ void gl16(const void* g, void* l) {
  __builtin_amdgcn_global_load_lds((const __attribute__((address_space(1))) u32*)g,
                                   (__attribute__((address_space(3))) u32*)l, 16, 0, 0);
}

// kv staging permutation: LDS K-row r holds token tokbase + PI(r).
// Chosen so swapped-QK^T output regs are exactly the PV A-fragment elements.
static __device__ __forceinline__ int PI(int r) {
  return ((r >> 2) & 3) * 8 + (r >> 5) * 32 + ((r >> 4) & 1) * 4 + (r & 3);
}

// ---------------- convert x (f32 -> bf16), 4 elems/thread ----------------
__global__ __launch_bounds__(256) void k_convert_x(const float* __restrict__ x,
                                                   u16* __restrict__ xb) {
  int i = blockIdx.x * 256 + threadIdx.x;        // 1,638,400 threads
  float4 v = ((const float4*)x)[i];
  ushort4 o;
  o.x = f2b(v.x); o.y = f2b(v.y); o.z = f2b(v.z); o.w = f2b(v.w);
  ((ushort4*)xb)[i] = o;
}

// ---------------- convert W (f32 -> bf16 transposed) ----------------
__global__ __launch_bounds__(256) void k_convert_w(const float* w0, const float* w1,
                                                   const float* w2, const float* w3,
                                                   u16* t0, u16* t1, u16* t2, u16* t3) {
  const float* W = (blockIdx.z == 0) ? w0 : (blockIdx.z == 1) ? w1 : (blockIdx.z == 2) ? w2 : w3;
  u16*         T = (blockIdx.z == 0) ? t0 : (blockIdx.z == 1) ? t1 : (blockIdx.z == 2) ? t2 : t3;
  __shared__ float tile[32][33];
  int tx = threadIdx.x & 31, ty = threadIdx.x >> 5;   // 32 x 8
  int n0 = blockIdx.x * 32, k0 = blockIdx.y * 32;
#pragma unroll
  for (int r = 0; r < 4; r++)
    tile[ty + 8 * r][tx] = W[(k0 + ty + 8 * r) * C_ + n0 + tx];
  __syncthreads();
#pragma unroll
  for (int r = 0; r < 4; r++)
    T[(n0 + ty + 8 * r) * C_ + k0 + tx] = f2b(tile[tx][ty + 8 * r]);
}

// ---------------- mask -> sel indices (order-preserving) ----------------
__global__ __launch_bounds__(1024) void k_scan(const float* __restrict__ mask,
                                               int* __restrict__ sel) {
  __shared__ int wcnt[16];
  __shared__ int carry;
  int tid = threadIdx.x, lane = tid & 63, wid = tid >> 6;
  float v[10];
#pragma unroll
  for (int r = 0; r < 10; r++) v[r] = mask[r * 1024 + tid];
  if (tid == 0) carry = 0;
  __syncthreads();
  for (int r = 0; r < 10; r++) {
    bool p = v[r] > 0.5f;
    unsigned long long b = __ballot(p);
    if (lane == 0) wcnt[wid] = __popcll(b);
    __syncthreads();
    int off = carry;
    for (int w = 0; w < wid; w++) off += wcnt[w];
    if (p) sel[off + __popcll(b & ((1ull << lane) - 1ull))] = r * 1024 + tid;
    __syncthreads();
    if (tid == 0) {
      int s = 0;
      for (int w = 0; w < 16; w++) s += wcnt[w];
      carry += s;
    }
    __syncthreads();
  }
}

#define QSCALE_ (1.4426950408889634f * 0.11180339887498949f)

// ---------------- fused QKV GEMM: grid 1200, which = f/400 ----------------
// which 0: K -> Kp padded; 1: V -> Vt transposed; 2: Q -> Qp padded+scaled.
// g = f%400: m = g%80, n = g/80 (XCD affinity: 400%8==0 and 80%8==0).
__global__ __launch_bounds__(256) void k_gemm_qkv(const u16* __restrict__ A,
                                                  const u16* __restrict__ WkT,
                                                  const u16* __restrict__ WvT,
                                                  const u16* __restrict__ WqT,
                                                  u16* __restrict__ Kp,
                                                  u16* __restrict__ Vt,
                                                  u16* __restrict__ Qp) {
  __shared__ u16 lA[128 * 32];
  __shared__ u16 lB[128 * 32];
  int tid = threadIdx.x, lane = tid & 63, wid = tid >> 6;
  int l15 = lane & 15, l4 = lane >> 4;
  int f = blockIdx.x;
  int which = f / 400, g = f % 400;
  const u16* BT = (which == 0) ? WkT : (which == 1) ? WvT : WqT;
  int m0 = (g % 80) * 128, n0 = (g / 80) * 128;
  int wr = wid >> 1, wc = wid & 1;
  int tok = tid >> 2, ch = tid & 3;
  int sc = ch ^ (tok & 3);                 // pre-swizzled source chunk
  f32x4 acc[4][4];
#pragma unroll
  for (int mi = 0; mi < 4; mi++)
#pragma unroll
    for (int ni = 0; ni < 4; ni++) acc[mi][ni] = (f32x4){0.f, 0.f, 0.f, 0.f};

  for (int k0 = 0; k0 < C_; k0 += 32) {
    __syncthreads();
    gl16(A  + (m0 + tok)      * C_ + k0 + sc * 8, (char*)lA + tid * 16);
    gl16(A  + (m0 + tok + 64) * C_ + k0 + sc * 8, (char*)lA + 4096 + tid * 16);
    gl16(BT + (n0 + tok)      * C_ + k0 + sc * 8, (char*)lB + tid * 16);
    gl16(BT + (n0 + tok + 64) * C_ + k0 + sc * 8, (char*)lB + 4096 + tid * 16);
    __syncthreads();
    bf16x8 af[4], bfr[4];
#pragma unroll
    for (int mi = 0; mi < 4; mi++) {
      int r = wr * 64 + mi * 16 + l15;
      af[mi] = *(const bf16x8*)((const char*)lA + r * 64 + ((l4 ^ (r & 3)) * 16));
    }
#pragma unroll
    for (int ni = 0; ni < 4; ni++) {
      int r = wc * 64 + ni * 16 + l15;
      bfr[ni] = *(const bf16x8*)((const char*)lB + r * 64 + ((l4 ^ (r & 3)) * 16));
    }
#pragma unroll
    for (int mi = 0; mi < 4; mi++)
#pragma unroll
      for (int ni = 0; ni < 4; ni++) acc[mi][ni] = MFMA16(af[mi], bfr[ni], acc[mi][ni]);
  }

  int cbase = n0 + wc * 64, rbase = m0 + wr * 64;
  if (which == 1) {
    // V: transposed [c][token]
#pragma unroll
    for (int mi = 0; mi < 4; mi++)
#pragma unroll
      for (int ni = 0; ni < 4; ni++) {
        int c = cbase + ni * 16 + l15;
        int r0 = rbase + mi * 16 + l4 * 4;
        ushort4 pk;
        pk.x = f2b(acc[mi][ni][0]); pk.y = f2b(acc[mi][ni][1]);
        pk.z = f2b(acc[mi][ni][2]); pk.w = f2b(acc[mi][ni][3]);
        *(ushort4*)(Vt + c * NKV_ + r0) = pk;
      }
  } else {
    u16* P = (which == 0) ? Kp : Qp;
    float sc2 = (which == 2) ? QSCALE_ : 1.f;
#pragma unroll
    for (int mi = 0; mi < 4; mi++)
#pragma unroll
      for (int ni = 0; ni < 4; ni++) {
        int c = cbase + ni * 16 + l15;
        int h = c / 80, d = c % 80;
#pragma unroll
        for (int rg = 0; rg < 4; rg++) {
          int r = rbase + mi * 16 + l4 * 4 + rg;
          P[r * CP_ + h * DP_ + d] = f2b(acc[mi][ni][rg] * sc2);
        }
      }
  }
}

// ---------------- O GEMM: C[M,N] = A[M,640] * BT[N,640]^T + bias ----------
__global__ __launch_bounds__(256) void k_gemm_o(const u16* __restrict__ A,
                                                const u16* __restrict__ BT,
                                                float* __restrict__ out,
                                                const float* __restrict__ bias) {
  __shared__ u16 lA[128 * 32];
  __shared__ u16 lB[128 * 32];
  int tid = threadIdx.x, lane = tid & 63, wid = tid >> 6;
  int l15 = lane & 15, l4 = lane >> 4;
  int f = blockIdx.x;
  int m0 = (f % 80) * 128, n0 = (f / 80) * 128;
  int wr = wid >> 1, wc = wid & 1;
  int tok = tid >> 2, ch = tid & 3;
  int sc = ch ^ (tok & 3);
  f32x4 acc[4][4];
#pragma unroll
  for (int mi = 0; mi < 4; mi++)
#pragma unroll
    for (int ni = 0; ni < 4; ni++) acc[mi][ni] = (f32x4){0.f, 0.f, 0.f, 0.f};

  for (int k0 = 0; k0 < C_; k0 += 32) {
    __syncthreads();
    gl16(A  + (m0 + tok)      * C_ + k0 + sc * 8, (char*)lA + tid * 16);
    gl16(A  + (m0 + tok + 64) * C_ + k0 + sc * 8, (char*)lA + 4096 + tid * 16);
    gl16(BT + (n0 + tok)      * C_ + k0 + sc * 8, (char*)lB + tid * 16);
    gl16(BT + (n0 + tok + 64) * C_ + k0 + sc * 8, (char*)lB + 4096 + tid * 16);
    __syncthreads();
    bf16x8 af[4], bfr[4];
#pragma unroll
    for (int mi = 0; mi < 4; mi++) {
      int r = wr * 64 + mi * 16 + l15;
      af[mi] = *(const bf16x8*)((const char*)lA + r * 64 + ((l4 ^ (r & 3)) * 16));
    }
#pragma unroll
    for (int ni = 0; ni < 4; ni++) {
      int r = wc * 64 + ni * 16 + l15;
      bfr[ni] = *(const bf16x8*)((const char*)lB + r * 64 + ((l4 ^ (r & 3)) * 16));
    }
#pragma unroll
    for (int mi = 0; mi < 4; mi++)
#pragma unroll
      for (int ni = 0; ni < 4; ni++) acc[mi][ni] = MFMA16(af[mi], bfr[ni], acc[mi][ni]);
  }

  int cbase = n0 + wc * 64, rbase = m0 + wr * 64;
#pragma unroll
  for (int ni = 0; ni < 4; ni++) {
    int c = cbase + ni * 16 + l15;
    float bv = bias[c];
#pragma unroll
    for (int mi = 0; mi < 4; mi++)
#pragma unroll
      for (int rg = 0; rg < 4; rg++)
        out[(rbase + mi * 16 + l4 * 4 + rg) * C_ + c] = acc[mi][ni][rg] + bv;
  }
}

// ---------------- gather sel rows into Kp, sel cols into Vt ----------------
__global__ __launch_bounds__(256) void k_gather(const int* __restrict__ sel,
                                                u16* __restrict__ Kp,
                                                u16* __restrict__ Vt) {
  int i = blockIdx.x;            // 0..2047
  int t = threadIdx.x;
  int s = sel[i];
  const u32* src = (const u32*)(Kp + s * CP_);
  u32* dst = (u32*)(Kp + (NTOK_ + i) * CP_);
  dst[t] = src[t];
  if (t < 128) dst[256 + t] = src[256 + t];
  for (int c = t; c < C_; c += 256)
    Vt[c * NKV_ + NTOK_ + i] = Vt[c * NKV_ + s];
}

// ---------------- flash attention (exact round-8 config, known-good) ------
// Grid 640 x 256 (4 waves x 32 q-rows), __launch_bounds__(256,2), 2-buffer
// LDS, batched reg loads, no-max softmax, cvtpk pack, zero-filled K=32 tail.
// Measured: 136 us, absmax 1.95e-3 (passed rounds 8/12-equivalent builds).
// NOTE: (256,3) with this register footprint produced NaN (round 15) -- the
// ~170-VGPR cap forces spill/remat on the ~200-reg transient fragment set.
// Keep (256,2).
__global__ __launch_bounds__(256, 2) void k_attn(const u16* __restrict__ Qp,
                                                 const u16* __restrict__ Kp,
                                                 const u16* __restrict__ Vt,
                                                 u16* __restrict__ Ob) {
  __shared__ u16 smem[2][10240];    // 2 x 20,480 B: Kx32 8192 | Ktail 2048 | V 10240
  int tid = threadIdx.x, lane = tid & 63, wid = tid >> 6;
  int l15 = lane & 15, l4 = lane >> 4;
  int f = blockIdx.x;
  int b = f & 15, h = (f >> 4) & 7, qt = f >> 7;   // XCD frame affinity
  int q0 = qt * 128 + wid * 32;
  const int NT = 42;
  const bf16x8 kz = {0, 0, 0, 0, 0, 0, 0, 0};

  // Q fragments (pre-scaled by log2e/sqrt(d) in Qp); MFMA B-operand.
  bf16x8 qf[2][2], qtl[2];
#pragma unroll
  for (int m = 0; m < 2; m++) {
    const u16* qrow = Qp + (size_t)(b * N_ + q0 + m * 16 + l15) * CP_ + h * DP_;
#pragma unroll
    for (int kk = 0; kk < 2; kk++)
      qf[m][kk] = *(const bf16x8*)(qrow + kk * 32 + l4 * 8);
    qtl[m] = (l4 < 2) ? *(const bf16x8*)(qrow + 64 + l4 * 8) : kz;
  }

  f32x4 o[2][5];
#pragma unroll
  for (int m = 0; m < 2; m++)
#pragma unroll
    for (int d5 = 0; d5 < 5; d5++) o[m][d5] = (f32x4){0.f, 0.f, 0.f, 0.f};
  float li_[2] = {0.f, 0.f};        // per-lane partial sums of P

  // staging: 1280 slots of 16B, 5 per thread, LDS dest linear (tid*16+k*4096).
  // slot < 512: K x32 [kk][tok][c]; 512..639: K tail [tok][ch]; 640+: V [vd][c].
  u32 gof[5];
#pragma unroll
  for (int k = 0; k < 5; k++) {
    int s = tid + 256 * k;
    if (s < 512) {
      int kk = s >> 8, rem = s & 255, tok = rem >> 2, c = rem & 3;
      gof[k] = (u32)(PI(tok) * CP_ + h * DP_ + kk * 32 + ((c ^ (tok & 3)) * 8));
    } else if (s < 640) {
      int j = s - 512, tok = j >> 1, ch = j & 1;
      gof[k] = (u32)(PI(tok) * CP_ + h * DP_ + 64 + ch * 8);
    } else {
      int j = s - 640, vd = j >> 3, c = j & 7;
      gof[k] = (u32)((h * D_ + vd) * NKV_ + ((c ^ (vd & 7)) * 8));
    }
  }

  auto stage = [&](int g, int buf) {
    int tokbase = (g < 10) ? (b * N_ + g * 64) : (NTOK_ + (g - 10) * 64);
    size_t kadd = (size_t)tokbase * CP_;
    char* dst = (char*)smem[buf] + tid * 16;
#pragma unroll
    for (int k = 0; k < 5; k++) {
      bool isv = (k >= 3) || (k == 2 && tid >= 128);
      const u16* src = isv ? (Vt + gof[k] + tokbase) : (Kp + gof[k] + kadd);
      gl16(src, dst + k * 4096);
    }
  };

  stage(0, 0);
  __syncthreads();
  int cur = 0;

  for (int tt = 0; tt < NT; tt++) {
    if (tt + 1 < NT) stage(tt + 1, cur ^ 1);
    const char* kb0 = (const char*)smem[cur];
    const char* vb0 = kb0 + 10240;

    // ---- batched register loads: all K frags, then all V frags ----
    bf16x8 kb[8];
#pragma unroll
    for (int kk = 0; kk < 2; kk++)
#pragma unroll
      for (int nt = 0; nt < 4; nt++) {
        int tk = nt * 16 + l15;
        kb[kk * 4 + nt] = *(const bf16x8*)(kb0 + kk * 4096 + tk * 64 + ((l4 ^ (tk & 3)) * 16));
      }
    bf16x8 kt[4];
#pragma unroll
    for (int nt = 0; nt < 4; nt++) {
      int tk = nt * 16 + l15;
      bf16x8 t = *(const bf16x8*)(kb0 + 8192 + tk * 32 + ((l4 & 1) * 16));
      kt[nt] = (l4 < 2) ? t : kz;
    }
    bf16x8 vb[10];
#pragma unroll
    for (int kk2 = 0; kk2 < 2; kk2++)
#pragma unroll
      for (int d5 = 0; d5 < 5; d5++) {
        int dd = d5 * 16 + l15;
        vb[kk2 * 5 + d5] =
            *(const bf16x8*)(vb0 + dd * 128 + (((kk2 * 4 + l4) ^ (dd & 7)) * 16));
      }

    // QK^T swapped: S^T; C col = q (l15), reg rows = kv (PI-permuted)
    f32x4 s[2][4];
#pragma unroll
    for (int m = 0; m < 2; m++)
#pragma unroll
      for (int nt = 0; nt < 4; nt++) s[m][nt] = (f32x4){0.f, 0.f, 0.f, 0.f};
    __builtin_amdgcn_s_setprio(1);
#pragma unroll
    for (int kk = 0; kk < 2; kk++)
#pragma unroll
      for (int nt = 0; nt < 4; nt++) {
        s[0][nt] = MFMA16(kb[kk * 4 + nt], qf[0][kk], s[0][nt]);
        s[1][nt] = MFMA16(kb[kk * 4 + nt], qf[1][kk], s[1][nt]);
      }
#pragma unroll
    for (int nt = 0; nt < 4; nt++) {      // tail dims 64..79 (zero-filled K=32)
      s[0][nt] = MFMA16(kt[nt], qtl[0], s[0][nt]);
      s[1][nt] = MFMA16(kt[nt], qtl[1], s[1][nt]);
    }
    __builtin_amdgcn_s_setprio(0);

    // P = exp2(S) directly (no max, no rescale) + per-lane partial sum
#pragma unroll
    for (int m = 0; m < 2; m++) {
#pragma unroll
      for (int nt = 0; nt < 4; nt++)
#pragma unroll
        for (int rg = 0; rg < 4; rg++)
          s[m][nt][rg] = exp2f(s[m][nt][rg]);
      f32x4 ps = (s[m][0] + s[m][1]) + (s[m][2] + s[m][3]);
      li_[m] += (ps[0] + ps[1]) + (ps[2] + ps[3]);
    }

    // pack P regs directly into PV A-fragments via v_cvt_pk_bf16_f32
    bf16x8 pa[2][2];
#pragma unroll
    for (int m = 0; m < 2; m++)
#pragma unroll
      for (int kk2 = 0; kk2 < 2; kk2++) {
        u32x4 w;
        w.x = cvtpk(s[m][2 * kk2][0],     s[m][2 * kk2][1]);
        w.y = cvtpk(s[m][2 * kk2][2],     s[m][2 * kk2][3]);
        w.z = cvtpk(s[m][2 * kk2 + 1][0], s[m][2 * kk2 + 1][1]);
        w.w = cvtpk(s[m][2 * kk2 + 1][2], s[m][2 * kk2 + 1][3]);
        pa[m][kk2] = __builtin_bit_cast(bf16x8, w);
      }

    // PV from registers
    __builtin_amdgcn_s_setprio(1);
#pragma unroll
    for (int kk2 = 0; kk2 < 2; kk2++)
#pragma unroll
      for (int d5 = 0; d5 < 5; d5++) {
        o[0][d5] = MFMA16(pa[0][kk2], vb[kk2 * 5 + d5], o[0][d5]);
        o[1][d5] = MFMA16(pa[1][kk2], vb[kk2 * 5 + d5], o[1][d5]);
      }
    __builtin_amdgcn_s_setprio(0);

    __syncthreads();               // drains vmcnt: next buffer ready
    cur ^= 1;
  }

  // epilogue: one cross-lane row-sum reduce, then O / l -> Ob bf16
#pragma unroll
  for (int m = 0; m < 2; m++) {
    li_[m] += __shfl_xor(li_[m], 16);
    li_[m] += __shfl_xor(li_[m], 32);
  }
#pragma unroll
  for (int m = 0; m < 2; m++)
#pragma unroll
    for (int rg = 0; rg < 4; rg++) {
      float lv = __shfl(li_[m], l4 * 4 + rg);
      float inv = 1.f / lv;
#pragma unroll
      for (int d5 = 0; d5 < 5; d5++) {
        int r = b * N_ + q0 + m * 16 + l4 * 4 + rg;
        Ob[(size_t)r * C_ + h * D_ + d5 * 16 + l15] = f2b(o[m][d5][rg] * inv);
      }
    }
}

// ---------------- launch ----------------
extern "C" void kernel_launch(void* const* d_in, const int* in_sizes, int n_in,
                              void* d_out, int out_size, void* d_ws, size_t ws_size,
                              hipStream_t stream) {
  (void)in_sizes; (void)n_in; (void)out_size; (void)ws_size;
  const float* x    = (const float*)d_in[0];
  const float* Wq   = (const float*)d_in[1];
  const float* Wk   = (const float*)d_in[2];
  const float* Wv   = (const float*)d_in[3];
  const float* Wo   = (const float*)d_in[4];
  const float* bo   = (const float*)d_in[5];
  const float* mask = (const float*)d_in[6];

  // Workspace layout (peak 66,723,840 B). Ob aliases xb (xb's last reader
  // k_gemm_qkv precedes the first Ob write, stream-ordered).
  char* ws = (char*)d_ws;
  u16* xb  = (u16*)(ws + 0);          // 13,107,200
  u16* Ob  = xb;                      // alias (see above)
  u16* WqT = (u16*)(ws + 13107200);   //    819,200
  u16* WkT = (u16*)(ws + 13926400);
  u16* WvT = (u16*)(ws + 14745600);
  u16* WoT = (u16*)(ws + 15564800);
  u16* Qp  = (u16*)(ws + 16384000);   // 15,728,640
  u16* Kp  = (u16*)(ws + 32112640);   // 18,874,368
  u16* Vt  = (u16*)(ws + 50987008);   // 15,728,640
  int* sel = (int*)(ws + 66715648);   //      8,192

  k_convert_x<<<6400, 256, 0, stream>>>(x, xb);
  k_convert_w<<<dim3(20, 20, 4), 256, 0, stream>>>(Wq, Wk, Wv, Wo, WqT, WkT, WvT, WoT);
  k_scan<<<1, 1024, 0, stream>>>(mask, sel);
  k_gemm_qkv<<<1200, 256, 0, stream>>>(xb, WkT, WvT, WqT, Kp, Vt, Qp);
  k_gather<<<2048, 256, 0, stream>>>(sel, Kp, Vt);
  k_attn<<<640, 256, 0, stream>>>(Qp, Kp, Vt, Ob);
  k_gemm_o<<<400, 256, 0, stream>>>(Ob, WoT, (float*)d_out, bo);
}